// Round 1
// baseline (263.391 us; speedup 1.0000x reference)
//
#include <hip/hip_runtime.h>
#include <hip/hip_bf16.h>

// Problem constants (fixed by setup_inputs): B=4, D=32, H=512, W=512, K=16
#define B_ 4
#define D_ 32
#define H_ 512
#define W_ 512
#define K_ 16
#define N_ (H_ * W_)   // 262144 pixels per image

// Workspace layout (float indices):
//   [0   ..  63]  sum[b][k]   attract hinged sums (atomically accumulated)
//   [64  .. 127]  cnt[b][k]   mask counts (float, exact integers)
//   [128 .. 191]  e2[b][k]    |E_k|^2
//   [192 .. 255]  labc[b][k]  (stored as int32, reinterpret)
//   [256 .. 259]  s_rep[b]
//   [260 .. 263]  s_reg[b]
//   [264 .. 2311] E[b][k][d]  (b*512 + k*32 + d)
#define WS_SUM  0
#define WS_CNT  64
#define WS_E2   128
#define WS_LAB  192
#define WS_REP  256
#define WS_REG  260
#define WS_E    264

__global__ __launch_bounds__(256) void setup_kernel(
    const float* __restrict__ outp, const int* __restrict__ target,
    const int* __restrict__ centers, float* __restrict__ ws) {
  const int b = blockIdx.x;
  const int tid = threadIdx.x;
  __shared__ float sE[K_ * D_];
  __shared__ float se2[K_];
  __shared__ float sred[256];

  // Zero the attract accumulators for this image (ws is poisoned 0xAA).
  if (tid < K_) {
    ws[WS_SUM + b * K_ + tid] = 0.0f;
    ws[WS_CNT + b * K_ + tid] = 0.0f;
  }

  // Gather E[k][d] = out[b, d, cy_k, cx_k]
  for (int i = tid; i < K_ * D_; i += 256) {
    const int k = i >> 5, d = i & 31;
    const int cy = centers[(b * K_ + k) * 2 + 0];
    const int cx = centers[(b * K_ + k) * 2 + 1];
    const float v = outp[(((size_t)b * D_ + d) * H_ + cy) * W_ + cx];
    sE[i] = v;
    ws[WS_E + b * (K_ * D_) + i] = v;
  }
  __syncthreads();

  // e2 and labels at centers
  if (tid < K_) {
    const int k = tid;
    float s = 0.0f;
    for (int d = 0; d < D_; ++d) s = fmaf(sE[k * D_ + d], sE[k * D_ + d], s);
    se2[k] = s;
    ws[WS_E2 + b * K_ + k] = s;
    const int cy = centers[(b * K_ + k) * 2 + 0];
    const int cx = centers[(b * K_ + k) * 2 + 1];
    ((int*)ws)[WS_LAB + b * K_ + k] = target[(size_t)b * N_ + cy * W_ + cx];
  }
  __syncthreads();

  // Repulse term: all 256 (i,j) pairs
  {
    const int i = tid >> 4, j = tid & 15;
    float dot = 0.0f;
    for (int d = 0; d < D_; ++d) dot = fmaf(sE[i * D_ + d], sE[j * D_ + d], dot);
    const float d2 = se2[i] + se2[j] - 2.0f * dot;
    const float dist = sqrtf(fmaxf(d2, 0.0f));
    sred[tid] = fmaxf(1.0f - dist, 0.0f);   // DELTA_R = 1.0
  }
  __syncthreads();
  for (int s = 128; s > 0; s >>= 1) {
    if (tid < s) sred[tid] += sred[tid + s];
    __syncthreads();
  }
  if (tid == 0) {
    ws[WS_REP + b] = sred[0] - (float)K_ * 1.0f;  // - K*DELTA_R
    float s = 0.0f;
    for (int k = 0; k < K_; ++k) s += sqrtf(fmaxf(se2[k], 0.0f));
    ws[WS_REG + b] = s;
  }
}

__global__ __launch_bounds__(256) void attract_kernel(
    const float* __restrict__ outp, const int* __restrict__ target,
    float* __restrict__ ws) {
  const int b = blockIdx.y;
  const int tid = threadIdx.x;
  __shared__ float sE[K_ * D_];
  __shared__ float se2[K_];
  __shared__ int slab[K_];
  __shared__ float sredh[K_];
  __shared__ float sredc[K_];

  const float* wsE = ws + WS_E + b * (K_ * D_);
  for (int i = tid; i < K_ * D_; i += 256) sE[i] = wsE[i];
  if (tid < K_) {
    se2[tid] = ws[WS_E2 + b * K_ + tid];
    slab[tid] = ((const int*)ws)[WS_LAB + b * K_ + tid];
    sredh[tid] = 0.0f;
    sredc[tid] = 0.0f;
  }
  __syncthreads();

  float hsum[K_];
  float fcnt[K_];
#pragma unroll
  for (int k = 0; k < K_; ++k) { hsum[k] = 0.0f; fcnt[k] = 0.0f; }

  const float* xb = outp + (size_t)b * D_ * N_;
  const int* tb = target + (size_t)b * N_;

  for (int n = blockIdx.x * 256 + tid; n < N_; n += 256 * gridDim.x) {
    float x[D_];
#pragma unroll
    for (int d = 0; d < D_; ++d) x[d] = xb[(size_t)d * N_ + n];
    const int lab = tb[n];
    float x2 = 0.0f;
#pragma unroll
    for (int d = 0; d < D_; ++d) x2 = fmaf(x[d], x[d], x2);

#pragma unroll
    for (int k = 0; k < K_; ++k) {
      const bool m = (lab == slab[k]);
      if (__any(m)) {   // labels partition pixels: usually 1-2 of 16 taken per wave
        float dot = 0.0f;
#pragma unroll
        for (int d = 0; d < D_; ++d) dot = fmaf(x[d], sE[k * D_ + d], dot);
        const float d2 = x2 + se2[k] - 2.0f * dot;
        const float dist = sqrtf(fmaxf(d2, 0.0f));
        const float h = fmaxf(dist - 0.1f, 0.0f);   // DELTA_A = 0.1
        if (m) { hsum[k] += h; fcnt[k] += 1.0f; }
      }
    }
  }

  // Wave-level butterfly reduction (wave = 64)
#pragma unroll
  for (int k = 0; k < K_; ++k) {
    float h = hsum[k], c = fcnt[k];
    for (int off = 32; off > 0; off >>= 1) {
      h += __shfl_xor(h, off, 64);
      c += __shfl_xor(c, off, 64);
    }
    hsum[k] = h;
    fcnt[k] = c;
  }
  if ((tid & 63) == 0) {
#pragma unroll
    for (int k = 0; k < K_; ++k) {
      atomicAdd(&sredh[k], hsum[k]);
      atomicAdd(&sredc[k], fcnt[k]);
    }
  }
  __syncthreads();
  if (tid < K_) {
    atomicAdd(&ws[WS_SUM + b * K_ + tid], sredh[tid]);
    atomicAdd(&ws[WS_CNT + b * K_ + tid], sredc[tid]);
  }
}

__global__ void final_kernel(const float* __restrict__ ws, float* __restrict__ out) {
  if (threadIdx.x == 0 && blockIdx.x == 0) {
    float att = 0.0f, rep = 0.0f, reg = 0.0f;
    for (int b = 0; b < B_; ++b) {
      float sa = 0.0f;
      for (int k = 0; k < K_; ++k) {
        const float c = ws[WS_CNT + b * K_ + k];
        const float denom = fmaxf(c - 1.0f, 1.0f);
        sa += ws[WS_SUM + b * K_ + k] / denom;
      }
      att = (att + sa) / (float)K_;                    // div_att = K
      rep = (rep + ws[WS_REP + b]) / (float)(K_ * (K_ - 1));  // div_rep = K*(K-1)
      reg = (reg + ws[WS_REG + b]) / (float)K_;        // div_reg = K
    }
    out[0] = 1.0f * att + 1.0f * rep + 0.001f * reg;   // ALPHA, BETA, GAMMA
    out[1] = att;
    out[2] = rep;
  }
}

extern "C" void kernel_launch(void* const* d_in, const int* in_sizes, int n_in,
                              void* d_out, int out_size, void* d_ws, size_t ws_size,
                              hipStream_t stream) {
  const float* outp = (const float*)d_in[0];
  const int* target = (const int*)d_in[1];
  const int* centers = (const int*)d_in[2];
  float* ws = (float*)d_ws;
  float* out = (float*)d_out;

  setup_kernel<<<dim3(B_), 256, 0, stream>>>(outp, target, centers, ws);
  attract_kernel<<<dim3(256, B_), 256, 0, stream>>>(outp, target, ws);
  final_kernel<<<1, 64, 0, stream>>>(ws, out);
}

// Round 2
// 210.843 us; speedup vs baseline: 1.2492x; 1.2492x over previous
//
#include <hip/hip_runtime.h>
#include <hip/hip_bf16.h>

// Problem constants (fixed by setup_inputs): B=4, D=32, H=512, W=512, K=16
#define B_ 4
#define D_ 32
#define H_ 512
#define W_ 512
#define K_ 16
#define N_ (H_ * W_)    // 262144 pixels per image
#define NQ_ (N_ / 4)    // 65536 float4-quads per image
#define PADK 17         // per-thread LDS accumulator stride (conflict-free: 17 coprime 32)
#define EPAD 33         // sE row pad (bank = (k+d)%32, conflict-free for per-lane k)

// Workspace layout (float indices):
#define WS_SUM  0    // [64]  sum[b][k]
#define WS_CNT  64   // [64]  cnt[b][k]
#define WS_E2   128  // [64]  |E_k|^2
#define WS_LAB  192  // [64]  label at center (int32 reinterpret)
#define WS_E    264  // [2048] E[b][k][d]

__global__ __launch_bounds__(64) void setup_kernel(
    const float* __restrict__ outp, const int* __restrict__ target,
    const int* __restrict__ centers, float* __restrict__ ws) {
  const int b = blockIdx.x, k = blockIdx.y;
  const int lane = threadIdx.x;
  const int cy = centers[(b * K_ + k) * 2 + 0];
  const int cx = centers[(b * K_ + k) * 2 + 1];
  float v = 0.0f;
  if (lane < D_) {
    v = outp[(((size_t)b * D_ + lane) * H_ + cy) * W_ + cx];
    ws[WS_E + (b * K_ + k) * D_ + lane] = v;
  }
  float s = v * v;
  for (int off = 32; off > 0; off >>= 1) s += __shfl_xor(s, off, 64);
  if (lane == 0) {
    ws[WS_E2 + b * K_ + k] = s;
    ((int*)ws)[WS_LAB + b * K_ + k] = target[(size_t)b * N_ + cy * W_ + cx];
    ws[WS_SUM + b * K_ + k] = 0.0f;  // ws is poisoned 0xAA — zero accumulators
    ws[WS_CNT + b * K_ + k] = 0.0f;
  }
}

__global__ __launch_bounds__(256) void attract_kernel(
    const float* __restrict__ outp, const int* __restrict__ target,
    float* __restrict__ ws) {
  const int b = blockIdx.y;
  const int tid = threadIdx.x;
  __shared__ float sE[K_ * EPAD];
  __shared__ float se2[K_];
  __shared__ int slab[K_];
  __shared__ float sacc[256 * PADK];  // per-thread hinge sums per k
  __shared__ float scnt[256 * PADK];  // per-thread counts per k

  for (int i = tid; i < K_ * D_; i += 256) {
    const int k = i >> 5, d = i & 31;
    sE[k * EPAD + d] = ws[WS_E + b * (K_ * D_) + i];
  }
  if (tid < K_) {
    se2[tid] = ws[WS_E2 + b * K_ + tid];
    slab[tid] = ((const int*)ws)[WS_LAB + b * K_ + tid];
  }
#pragma unroll
  for (int k = 0; k < K_; ++k) {
    sacc[tid * PADK + k] = 0.0f;
    scnt[tid * PADK + k] = 0.0f;
  }
  __syncthreads();

  // Exactly one quad per thread: q in [0, 65536)
  const int q = blockIdx.x * 256 + tid;
  const float4* xb4 = (const float4*)(outp + (size_t)b * D_ * N_);
  const int4 lab4 = ((const int4*)(target + (size_t)b * N_))[q];
  const int labv[4] = {lab4.x, lab4.y, lab4.z, lab4.w};

  int kf[4], nm[4];
#pragma unroll
  for (int j = 0; j < 4; ++j) {
    kf[j] = 0; nm[j] = 0;
#pragma unroll
    for (int k = 0; k < K_; ++k) {
      if (labv[j] == slab[k]) { if (nm[j] == 0) kf[j] = k; nm[j]++; }
    }
  }

  float dot[4] = {0.f, 0.f, 0.f, 0.f};
  float x2[4] = {0.f, 0.f, 0.f, 0.f};
#pragma unroll 8
  for (int d = 0; d < D_; ++d) {
    const float4 x = xb4[(size_t)d * NQ_ + q];
    const float xs[4] = {x.x, x.y, x.z, x.w};
#pragma unroll
    for (int j = 0; j < 4; ++j) {
      const float e = sE[kf[j] * EPAD + d];  // per-lane row; pad makes it conflict-free
      dot[j] = fmaf(xs[j], e, dot[j]);
      x2[j] = fmaf(xs[j], xs[j], x2[j]);
    }
  }

#pragma unroll
  for (int j = 0; j < 4; ++j) {
    if (nm[j] > 0) {
      const int k = kf[j];
      const float d2 = x2[j] + se2[k] - 2.0f * dot[j];
      const float h = fmaxf(sqrtf(fmaxf(d2, 0.0f)) - 0.1f, 0.0f);  // DELTA_A=0.1
      sacc[tid * PADK + k] += h;
      scnt[tid * PADK + k] += 1.0f;
    }
  }

  // Rare general case: duplicate-label centers (never taken on this input).
  const bool extra = (nm[0] > 1) | (nm[1] > 1) | (nm[2] > 1) | (nm[3] > 1);
  if (__any(extra)) {
    for (int k = 0; k < K_; ++k) {
      bool need[4]; bool anyn = false;
#pragma unroll
      for (int j = 0; j < 4; ++j) {
        need[j] = (nm[j] > 1) && (labv[j] == slab[k]) && (k != kf[j]);
        anyn |= need[j];
      }
      if (__any(anyn)) {
        float dt[4] = {0.f, 0.f, 0.f, 0.f};
        for (int d = 0; d < D_; ++d) {
          const float4 x = xb4[(size_t)d * NQ_ + q];
          const float xs[4] = {x.x, x.y, x.z, x.w};
#pragma unroll
          for (int j = 0; j < 4; ++j)
            if (need[j]) dt[j] = fmaf(xs[j], sE[k * EPAD + d], dt[j]);
        }
#pragma unroll
        for (int j = 0; j < 4; ++j) {
          if (need[j]) {
            const float d2 = x2[j] + se2[k] - 2.0f * dt[j];
            const float h = fmaxf(sqrtf(fmaxf(d2, 0.0f)) - 0.1f, 0.0f);
            sacc[tid * PADK + k] += h;
            scnt[tid * PADK + k] += 1.0f;
          }
        }
      }
    }
  }
  __syncthreads();

  // Block reduce, stage 1: 16 groups of 16 rows each
  const int r = tid >> 4, kk = tid & 15;
  float hsum = 0.0f, csum = 0.0f;
#pragma unroll
  for (int j = 0; j < 16; ++j) {
    hsum += sacc[(r * 16 + j) * PADK + kk];
    csum += scnt[(r * 16 + j) * PADK + kk];
  }
  __syncthreads();
  sacc[r * PADK + kk] = hsum;
  scnt[r * PADK + kk] = csum;
  __syncthreads();
  if (tid < K_) {
    float h = 0.0f, c = 0.0f;
#pragma unroll
    for (int rr = 0; rr < 16; ++rr) {
      h += sacc[rr * PADK + tid];
      c += scnt[rr * PADK + tid];
    }
    atomicAdd(&ws[WS_SUM + b * K_ + tid], h);
    atomicAdd(&ws[WS_CNT + b * K_ + tid], c);
  }
}

__global__ __launch_bounds__(256) void final_kernel(const float* __restrict__ ws,
                                                    float* __restrict__ out) {
  __shared__ float sE[B_ * K_ * D_];
  __shared__ float sred[256];
  __shared__ float srep[B_];
  __shared__ float sreg[B_];
  const int tid = threadIdx.x;
  for (int i = tid; i < B_ * K_ * D_; i += 256) sE[i] = ws[WS_E + i];
  __syncthreads();

  const int i = tid >> 4, j = tid & 15;
  for (int b = 0; b < B_; ++b) {
    float dotv = 0.0f;
    for (int d = 0; d < D_; ++d)
      dotv = fmaf(sE[(b * K_ + i) * D_ + d], sE[(b * K_ + j) * D_ + d], dotv);
    const float d2 = ws[WS_E2 + b * K_ + i] + ws[WS_E2 + b * K_ + j] - 2.0f * dotv;
    sred[tid] = fmaxf(1.0f - sqrtf(fmaxf(d2, 0.0f)), 0.0f);  // DELTA_R=1.0
    __syncthreads();
    for (int s = 128; s > 0; s >>= 1) {
      if (tid < s) sred[tid] += sred[tid + s];
      __syncthreads();
    }
    if (tid == 0) srep[b] = sred[0] - (float)K_;
    __syncthreads();
  }

  sred[tid] = (tid < B_ * K_) ? sqrtf(fmaxf(ws[WS_E2 + tid], 0.0f)) : 0.0f;
  __syncthreads();
  if (tid < B_) {
    float s = 0.0f;
    for (int k = 0; k < K_; ++k) s += sred[tid * K_ + k];
    sreg[tid] = s;
  }
  __syncthreads();

  if (tid == 0) {
    float att = 0.0f, rep = 0.0f, reg = 0.0f;
    for (int b = 0; b < B_; ++b) {
      float sa = 0.0f;
      for (int k = 0; k < K_; ++k) {
        const float c = ws[WS_CNT + b * K_ + k];
        sa += ws[WS_SUM + b * K_ + k] / fmaxf(c - 1.0f, 1.0f);
      }
      att = (att + sa) / (float)K_;
      rep = (rep + srep[b]) / (float)(K_ * (K_ - 1));
      reg = (reg + sreg[b]) / (float)K_;
    }
    out[0] = att + rep + 0.001f * reg;  // ALPHA=BETA=1, GAMMA=0.001
    out[1] = att;
    out[2] = rep;
  }
}

extern "C" void kernel_launch(void* const* d_in, const int* in_sizes, int n_in,
                              void* d_out, int out_size, void* d_ws, size_t ws_size,
                              hipStream_t stream) {
  const float* outp = (const float*)d_in[0];
  const int* target = (const int*)d_in[1];
  const int* centers = (const int*)d_in[2];
  float* ws = (float*)d_ws;
  float* out = (float*)d_out;

  setup_kernel<<<dim3(B_, K_), 64, 0, stream>>>(outp, target, centers, ws);
  attract_kernel<<<dim3(NQ_ / 256, B_), 256, 0, stream>>>(outp, target, ws);
  final_kernel<<<1, 256, 0, stream>>>(ws, out);
}